// Round 10
// baseline (384.346 us; speedup 1.0000x reference)
//
#include <hip/hip_runtime.h>
#include <hip/hip_bf16.h>
#include <stdint.h>

typedef __attribute__((ext_vector_type(8))) short short8;
typedef __attribute__((ext_vector_type(4))) short short4v;
typedef __attribute__((ext_vector_type(4))) float floatx4;
typedef __hip_bfloat16 bf16;

__device__ __forceinline__ float b2f(bf16 v) { return __bfloat162float(v); }
__device__ __forceinline__ bf16 f2b(float v) { return __float2bfloat16(v); }
__device__ __forceinline__ float gelu_f(float v) {
    return 0.5f * v * (1.0f + erff(v * 0.70710678118654752f));
}

#define GLD_LDS16(gptr, lptr) \
  __builtin_amdgcn_global_load_lds((const __attribute__((address_space(1))) void*)(gptr), \
                                   (__attribute__((address_space(3))) void*)(lptr), 16, 0, 0)

// ---------------- CSR build (group edges by dst), 4 edges/thread ----------------
__global__ void k_count(const int* __restrict__ dst, int* __restrict__ cnt, int E) {
    int g = blockIdx.x * blockDim.x + threadIdx.x;
    if (g * 4 < E) {
        int4 d = ((const int4*)dst)[g];
        atomicAdd(&cnt[d.x], 1);
        atomicAdd(&cnt[d.y], 1);
        atomicAdd(&cnt[d.z], 1);
        atomicAdd(&cnt[d.w], 1);
    }
}

// n must be 32768: 1024 threads x 32 elements each (int4 loads)
__global__ __launch_bounds__(1024) void k_scan(const int* __restrict__ cnt,
                                               int* __restrict__ row_ptr,
                                               int* __restrict__ fill, int n) {
    __shared__ int sdata[1024];
    int t = threadIdx.x;
    int base = t * 32;
    int local[32];
    const int4* c4 = (const int4*)(cnt + base);
    int vals[32];
    #pragma unroll
    for (int q = 0; q < 8; q++) {
        int4 v = c4[q];
        vals[q * 4 + 0] = v.x; vals[q * 4 + 1] = v.y;
        vals[q * 4 + 2] = v.z; vals[q * 4 + 3] = v.w;
    }
    int sum = 0;
    #pragma unroll
    for (int k = 0; k < 32; k++) { local[k] = sum; sum += vals[k]; }
    sdata[t] = sum;
    __syncthreads();
    for (int off = 1; off < 1024; off <<= 1) {
        int v = (t >= off) ? sdata[t - off] : 0;
        __syncthreads();
        sdata[t] += v;
        __syncthreads();
    }
    int excl = sdata[t] - sum;
    #pragma unroll
    for (int k = 0; k < 32; k++) {
        int v = excl + local[k];
        row_ptr[base + k] = v;
        fill[base + k] = v;
    }
    if (t == 1023) row_ptr[n] = excl + sum;
}

__global__ void k_scatter(const int* __restrict__ src, const int* __restrict__ dst,
                          int* __restrict__ fill, int* __restrict__ col, int E) {
    int g = blockIdx.x * blockDim.x + threadIdx.x;
    if (g * 4 < E) {
        int4 d = ((const int4*)dst)[g];
        int4 sv = ((const int4*)src)[g];
        int p;
        p = atomicAdd(&fill[d.x], 1); col[p] = sv.x;
        p = atomicAdd(&fill[d.y], 1); col[p] = sv.y;
        p = atomicAdd(&fill[d.z], 1); col[p] = sv.z;
        p = atomicAdd(&fill[d.w], 1); col[p] = sv.w;
    }
}

// ---------------- all four weight transposes (both layers) in one launch ----------------
// Wt[layer][512][256] bf16: rows 0..255 = W_l columns, 256..511 = W_r columns
__global__ void k_transpose4(const float* __restrict__ Wl1, const float* __restrict__ Wr1,
                             const float* __restrict__ Wl2, const float* __restrict__ Wr2,
                             bf16* __restrict__ Wt) {
    int r = blockIdx.x & 255, half = (blockIdx.x >> 8) & 1, layer = blockIdx.x >> 9;
    int c = threadIdx.x;
    const float* W = layer ? (half ? Wr2 : Wl2) : (half ? Wr1 : Wl1);
    Wt[(size_t)(layer * 512 + half * 256 + c) * 256 + r] = f2b(W[r * 256 + c]);
}

// ---------------- fused MFMA GEMM: C[M,512] = A[M,K] @ Bt[512,K]^T + bias ----------------
// grid (4, M/128). 128x128 tile, BK=64. B (and bf16-A) via global_load_lds (m97).
// Epilogue: acc -> padded LDS tile -> coalesced dwordx4 stores (256B row segments).
template <bool AF32>
__global__ __launch_bounds__(256) void k_gemm(const void* __restrict__ Av,
                                              const bf16* __restrict__ Bt,
                                              const float* __restrict__ biasL,
                                              const float* __restrict__ biasR,
                                              bf16* __restrict__ C,
                                              int M, int K) {
    __shared__ bf16 smem[16896];      // staging: As=smem[0:8192), Bs=smem[8192:16384)
    bf16* As = smem;                  // epilogue: 128x132 padded output tile
    bf16* Bs = smem + 8192;
    const int tid  = threadIdx.x;
    const int wave = tid >> 6;
    const int lane = tid & 63;
    const int quad = lane >> 4;
    const int l16  = lane & 15;
    const int m0 = blockIdx.y * 128;
    const int n0 = blockIdx.x * 128;
    const int wm = (wave & 1) * 64;
    const int wn = (wave >> 1) * 64;

    floatx4 acc[4][4] = {};

    for (int k0 = 0; k0 < K; k0 += 64) {
        #pragma unroll
        for (int i = 0; i < 4; i++) {
            if (AF32) {
                const float* A = (const float*)Av;
                int flat = (i * 256 + tid) * 8;
                int row  = flat >> 6;
                int colk = flat & 63;
                const float* ap = A + (size_t)(m0 + row) * K + k0 + colk;
                bf16 tmp[8];
                #pragma unroll
                for (int q = 0; q < 8; q++) tmp[q] = f2b(ap[q]);
                *(short8*)&As[row * 64 + colk] = *(const short8*)tmp;
            } else {
                const bf16* A = (const bf16*)Av;
                int chunk = i * 4 + wave;
                int foff  = (chunk * 64 + lane) * 16;
                int row   = foff >> 7;
                int cole  = (foff & 127) >> 1;
                GLD_LDS16(A + (size_t)(m0 + row) * K + k0 + cole,
                          (char*)As + chunk * 1024 + lane * 16);
            }
            {
                int chunk = i * 4 + wave;
                int foff  = (chunk * 64 + lane) * 16;
                int row   = foff >> 7;
                int cole  = (foff & 127) >> 1;
                GLD_LDS16(Bt + (size_t)(n0 + row) * K + k0 + cole,
                          (char*)Bs + chunk * 1024 + lane * 16);
            }
        }
        __syncthreads();
        #pragma unroll
        for (int ks = 0; ks < 2; ks++) {
            short8 af[4], bfr[4];
            #pragma unroll
            for (int i = 0; i < 4; i++) {
                af[i]  = *(const short8*)&As[(wm + i * 16 + l16) * 64 + ks * 32 + quad * 8];
                bfr[i] = *(const short8*)&Bs[(wn + i * 16 + l16) * 64 + ks * 32 + quad * 8];
            }
            #pragma unroll
            for (int i = 0; i < 4; i++)
                #pragma unroll
                for (int j = 0; j < 4; j++)
                    acc[i][j] = __builtin_amdgcn_mfma_f32_16x16x32_bf16(af[i], bfr[j], acc[i][j], 0, 0, 0);
        }
        __syncthreads();
    }

    // C/D layout: col = lane&15, row = quad*4 + reg  [verified m89/m91]
    // Stage into padded LDS (stride 132 elems) ...
    #pragma unroll
    for (int j = 0; j < 4; j++) {
        int lcol = wn + j * 16 + l16;
        int gcol = n0 + lcol;
        float bv = (gcol < 256) ? biasL[gcol] : biasR[gcol - 256];
        #pragma unroll
        for (int i = 0; i < 4; i++) {
            #pragma unroll
            for (int r = 0; r < 4; r++) {
                int lrow = wm + i * 16 + quad * 4 + r;
                smem[lrow * 132 + lcol] = f2b(acc[i][j][r] + bv);
            }
        }
    }
    __syncthreads();
    // ... then coalesced wide stores: 16 lanes cover one 256B row segment.
    {
        int rl = tid >> 4;            // 0..15: row within pass group
        int cs = (tid & 15) * 8;      // 8-elem column chunk
        #pragma unroll
        for (int p = 0; p < 8; p++) {
            int row = p * 16 + rl;
            short8 v = *(const short8*)&smem[row * 132 + cs];
            *(short8*)(C + (size_t)(m0 + row) * 512 + n0 + cs) = v;
        }
    }
}

// ---------------- GATv2 aggregation: half-wave per edge, 8 ch/lane, 4 edges/iter ----------------
// One wave per dst node. Lanes 0-31 = stream A (even items), 32-63 = stream B (odd items).
// Within a half: 8 lanes per head (hl>>3), 8 channels per lane ((hl&7)*8).
// Max-free softmax (logits bounded), leaky folded into att (0.6u + 0.4|u|).
// Self-loop hoisted; edge loop unrolled x2 (4 edges/iter) with 2-deep col+gather prefetch.
__global__ __launch_bounds__(256) void k_agg(const bf16* __restrict__ xlr,
                                             const float* __restrict__ att,
                                             const int* __restrict__ row_ptr,
                                             const int* __restrict__ col,
                                             const float* __restrict__ bias,
                                             bf16* __restrict__ out, int do_gelu) {
    int wave = threadIdx.x >> 6, lane = threadIdx.x & 63;
    int i = blockIdx.x * 4 + wave;
    int hl = lane & 31;
    int half = lane >> 5;
    int f = (hl >> 3) * 64 + (hl & 7) * 8;

    float att6[8], att4[8], xr_v[8], xs[8];
    {
        floatx4 a0 = *(const floatx4*)(att + f);
        floatx4 a1 = *(const floatx4*)(att + f + 4);
        #pragma unroll
        for (int j = 0; j < 4; j++) {
            att6[j]     = 0.6f * a0[j]; att4[j]     = 0.4f * a0[j];
            att6[4 + j] = 0.6f * a1[j]; att4[4 + j] = 0.4f * a1[j];
        }
        bf16 t[8];
        *(short8*)t = *(const short8*)(xlr + (size_t)i * 512 + 256 + f);
        #pragma unroll
        for (int j = 0; j < 8; j++) xr_v[j] = b2f(t[j]);
        *(short8*)t = *(const short8*)(xlr + (size_t)i * 512 + f);
        #pragma unroll
        for (int j = 0; j < 8; j++) xs[j] = b2f(t[j]);
    }

    // self-loop (both halves compute identically; only half 0 contributes)
    float lg = 0.f;
    #pragma unroll
    for (int j = 0; j < 8; j++) {
        float u = xs[j] + xr_v[j];
        lg = fmaf(u, att6[j], fmaf(fabsf(u), att4[j], lg));
    }
    lg += __shfl_xor(lg, 1, 8);
    lg += __shfl_xor(lg, 2, 8);
    lg += __shfl_xor(lg, 4, 8);
    float p0 = (half == 0) ? __expf(lg) : 0.f;
    float s = p0;
    float acc[8];
    #pragma unroll
    for (int j = 0; j < 8; j++) acc[j] = p0 * xs[j];

    int e0 = row_ptr[i];
    int deg = row_ptr[i + 1] - e0;

    // prologue: gathers for items {half, half+2}; cols for items {half+4, half+6}
    int t0 = half, t1 = half + 2;
    int s0 = (t0 < deg) ? col[e0 + t0] : i;
    int s1 = (t1 < deg) ? col[e0 + t1] : i;
    bf16 ga[8], gb[8];
    *(short8*)ga = *(const short8*)(xlr + (size_t)s0 * 512 + f);
    *(short8*)gb = *(const short8*)(xlr + (size_t)s1 * 512 + f);
    int t2 = half + 4, t3 = half + 6;
    int s2 = (t2 < deg) ? col[e0 + t2] : i;
    int s3 = (t3 < deg) ? col[e0 + t3] : i;

    for (int base = 0; base < deg; base += 4) {
        // issue gathers for next 4 items
        bf16 na[8], nb[8];
        *(short8*)na = *(const short8*)(xlr + (size_t)s2 * 512 + f);
        *(short8*)nb = *(const short8*)(xlr + (size_t)s3 * 512 + f);
        // resolve cols two iterations ahead
        int t4 = base + 8 + half, t5 = base + 10 + half;
        s2 = (t4 < deg) ? col[e0 + t4] : i;
        s3 = (t5 < deg) ? col[e0 + t5] : i;
        // compute current 4 items (2 per half)
        float xa[8], xb[8], la = 0.f, lb = 0.f;
        #pragma unroll
        for (int j = 0; j < 8; j++) {
            xa[j] = b2f(ga[j]);
            float ua = xa[j] + xr_v[j];
            la = fmaf(ua, att6[j], fmaf(fabsf(ua), att4[j], la));
            xb[j] = b2f(gb[j]);
            float ub = xb[j] + xr_v[j];
            lb = fmaf(ub, att6[j], fmaf(fabsf(ub), att4[j], lb));
        }
        la += __shfl_xor(la, 1, 8); lb += __shfl_xor(lb, 1, 8);
        la += __shfl_xor(la, 2, 8); lb += __shfl_xor(lb, 2, 8);
        la += __shfl_xor(la, 4, 8); lb += __shfl_xor(lb, 4, 8);
        float pa = ((base + half) < deg)     ? __expf(la) : 0.f;
        float pb = ((base + 2 + half) < deg) ? __expf(lb) : 0.f;
        s += pa + pb;
        #pragma unroll
        for (int j = 0; j < 8; j++)
            acc[j] = fmaf(pa, xa[j], fmaf(pb, xb[j], acc[j]));
        // rotate pipeline
        #pragma unroll
        for (int j = 0; j < 8; j++) { ga[j] = na[j]; gb[j] = nb[j]; }
    }

    // combine halves
    s += __shfl_xor(s, 32, 64);
    #pragma unroll
    for (int j = 0; j < 8; j++) acc[j] += __shfl_xor(acc[j], 32, 64);

    if (half == 0) {
        float inv = 1.0f / (s + 1e-16f);
        bf16 ov[8];
        #pragma unroll
        for (int j = 0; j < 8; j++) {
            float v = acc[j] * inv + bias[f + j];
            if (do_gelu) v = gelu_f(v);
            ov[j] = f2b(v);
        }
        *(short8*)(out + (size_t)i * 256 + f) = *(const short8*)ov;
    }
}

// ---------------- global mean pool, two-stage ----------------
__global__ __launch_bounds__(256) void k_pool1(const bf16* __restrict__ h,
                                               float* __restrict__ part,
                                               int per_graph, int rows_per) {
    int g = blockIdx.x, p = blockIdx.y, c = threadIdx.x;
    const bf16* base = h + ((size_t)g * per_graph + (size_t)p * rows_per) * 256;
    float acc = 0.f;
    for (int r = 0; r < rows_per; r++) acc += b2f(base[(size_t)r * 256 + c]);
    part[((size_t)g * gridDim.y + p) * 256 + c] = acc;
}
__global__ __launch_bounds__(256) void k_pool2(const float* __restrict__ part,
                                               float* __restrict__ out,
                                               int nparts, int per_graph) {
    int g = blockIdx.x, c = threadIdx.x;
    float acc = 0.f;
    for (int p = 0; p < nparts; p++) acc += part[((size_t)g * nparts + p) * 256 + c];
    out[g * 256 + c] = acc / (float)per_graph;
}

// ---------------- head layer: block per (graph, 64-col chunk), split-K ----------------
__global__ __launch_bounds__(256) void k_head2(const bf16* __restrict__ inB,
                                               const float* __restrict__ inF,
                                               const float* __restrict__ W,
                                               const float* __restrict__ bias,
                                               float* __restrict__ out,
                                               int K, int N, long long row_stride, int act) {
    __shared__ float zin[1024];
    __shared__ float red[256];
    int g = blockIdx.x;
    int t = threadIdx.x;
    int nc = t & 63;
    int kq = t >> 6;
    int n = blockIdx.y * 64 + nc;
    for (int k = t; k < K; k += 256)
        zin[k] = inB ? b2f(inB[(size_t)g * row_stride + k])
                     : inF[(size_t)g * row_stride + k];
    __syncthreads();
    const int klen = K >> 2;
    const int kb = kq * klen;
    float acc = 0.f;
    #pragma unroll 8
    for (int k = 0; k < klen; k++)
        acc = fmaf(zin[kb + k], W[(size_t)(kb + k) * N + n], acc);
    red[t] = acc;
    __syncthreads();
    if (kq == 0) {
        float v = red[nc] + red[nc + 64] + red[nc + 128] + red[nc + 192] + bias[n];
        if (act) v = gelu_f(v);
        out[(size_t)g * N + n] = v;
    }
}

extern "C" void kernel_launch(void* const* d_in, const int* in_sizes, int n_in,
                              void* d_out, int out_size, void* d_ws, size_t ws_size,
                              hipStream_t stream) {
    const float* x     = (const float*)d_in[0];
    const int*   ei    = (const int*)d_in[1];
    const float* w1_l  = (const float*)d_in[4];
    const float* b1_l  = (const float*)d_in[5];
    const float* w1_r  = (const float*)d_in[6];
    const float* b1_r  = (const float*)d_in[7];
    const float* att1  = (const float*)d_in[8];
    const float* bias1 = (const float*)d_in[9];
    const float* w2_l  = (const float*)d_in[10];
    const float* b2_l  = (const float*)d_in[11];
    const float* w2_r  = (const float*)d_in[12];
    const float* b2_r  = (const float*)d_in[13];
    const float* att2  = (const float*)d_in[14];
    const float* bias2 = (const float*)d_in[15];
    const float* lin1w = (const float*)d_in[16];
    const float* lin1b = (const float*)d_in[17];
    const float* lin2w = (const float*)d_in[18];
    const float* lin2b = (const float*)d_in[19];
    const float* finw  = (const float*)d_in[20];
    const float* finb  = (const float*)d_in[21];

    const int N  = in_sizes[0] / 256;   // 32768
    const int E  = in_sizes[1] / 2;     // 524288
    const int NG = 64;
    const int PG = N / NG;              // 512

    // workspace layout (~52.5 MiB), 16B-aligned blocks
    char* ws = (char*)d_ws;
    size_t off = 0;
    bf16* xlr = (bf16*)(ws + off); off += (size_t)N * 512 * 2;    // 32 MiB [xl|xr]
    bf16* hb  = (bf16*)(ws + off); off += (size_t)N * 256 * 2;    // 16 MiB (h1 then h2)
    bf16* wt  = (bf16*)(ws + off); off += 2 * 512 * 256 * 2;      // 512 KiB both layers' Wt
    int* row_ptr = (int*)(ws + off); off += (size_t)(N + 4) * 4;
    int* cnt     = (int*)(ws + off); off += (size_t)N * 4;
    int* fill    = (int*)(ws + off); off += (size_t)N * 4;
    int* col     = (int*)(ws + off); off += (size_t)E * 4;
    float* pws   = (float*)(ws + off); off += (size_t)NG * 8 * 256 * 4;  // pool partials
    float* t1    = (float*)(ws + off); off += (size_t)NG * 1024 * 4;
    float* t2    = (float*)(ws + off); off += (size_t)NG * 256 * 4;

    const int* srcv = ei;
    const int* dstv = ei + E;

    // --- CSR build ---
    hipMemsetAsync(cnt, 0, (size_t)N * 4, stream);
    k_count  <<<E / 1024, 256, 0, stream>>>(dstv, cnt, E);
    k_scan   <<<1, 1024, 0, stream>>>(cnt, row_ptr, fill, N);
    k_scatter<<<E / 1024, 256, 0, stream>>>(srcv, dstv, fill, col, E);

    // --- both layers' weight transposes, one launch ---
    k_transpose4<<<1024, 256, 0, stream>>>(w1_l, w1_r, w2_l, w2_r, wt);

    dim3 gg(4, N / 128);   // fused L/R: N-dim 512; A-sharing blocks dispatch-adjacent
    // --- layer 1 (A = x fp32) ---
    k_gemm<true><<<gg, 256, 0, stream>>>(x, wt, b1_l, b1_r, xlr, N, 256);
    k_agg<<<N / 4, 256, 0, stream>>>(xlr, att1, row_ptr, col, bias1, hb, 1);  // + GELU

    // --- layer 2 (A = h1 bf16) ---
    k_gemm<false><<<gg, 256, 0, stream>>>(hb, wt + 512 * 256, b2_l, b2_r, xlr, N, 256);
    k_agg<<<N / 4, 256, 0, stream>>>(xlr, att2, row_ptr, col, bias2, hb, 0);  // h2

    float* outp = (float*)d_out;
    // --- graph mean pool -> d_out[64*512 ..] (output 1) ---
    {
        dim3 gp(NG, 8);
        k_pool1<<<gp, 256, 0, stream>>>(hb, pws, PG, PG / 8);
        k_pool2<<<NG, 256, 0, stream>>>(pws, outp + 64 * 512, 8, PG);
    }
    // --- MLP head on node 0 of each graph -> d_out[0 .. 64*512) (output 0) ---
    {
        dim3 h1(NG, 1024 / 64);
        k_head2<<<h1, 256, 0, stream>>>(hb, nullptr, lin1w, lin1b, t1,
                                        256, 1024, (long long)PG * 256, 1);
        dim3 h2(NG, 256 / 64);
        k_head2<<<h2, 256, 0, stream>>>(nullptr, t1, lin2w, lin2b, t2,
                                        1024, 256, 1024, 0);
        dim3 h3(NG, 512 / 64);
        k_head2<<<h3, 256, 0, stream>>>(nullptr, t2, finw, finb, outp,
                                        256, 512, 256, 0);
    }
}

// Round 11
// 365.433 us; speedup vs baseline: 1.0518x; 1.0518x over previous
//
#include <hip/hip_runtime.h>
#include <hip/hip_bf16.h>
#include <stdint.h>

typedef __attribute__((ext_vector_type(8))) short short8;
typedef __attribute__((ext_vector_type(4))) short short4v;
typedef __attribute__((ext_vector_type(4))) float floatx4;
typedef __hip_bfloat16 bf16;

__device__ __forceinline__ float b2f(bf16 v) { return __bfloat162float(v); }
__device__ __forceinline__ bf16 f2b(float v) { return __float2bfloat16(v); }
__device__ __forceinline__ float gelu_f(float v) {
    return 0.5f * v * (1.0f + erff(v * 0.70710678118654752f));
}

#define GLD_LDS16(gptr, lptr) \
  __builtin_amdgcn_global_load_lds((const __attribute__((address_space(1))) void*)(gptr), \
                                   (__attribute__((address_space(3))) void*)(lptr), 16, 0, 0)

// ---------------- fused: CSR count (blocks 0..511) + weight transposes (512..1535) ----------------
// Wt[layer][512][256] bf16: rows 0..255 = W_l columns, 256..511 = W_r columns
__global__ void k_count_tr(const int* __restrict__ dst, int* __restrict__ cnt, int E,
                           const float* __restrict__ Wl1, const float* __restrict__ Wr1,
                           const float* __restrict__ Wl2, const float* __restrict__ Wr2,
                           bf16* __restrict__ Wt) {
    int bx = blockIdx.x;
    if (bx < 512) {
        int g = bx * 256 + threadIdx.x;
        if (g * 4 < E) {
            int4 d = ((const int4*)dst)[g];
            atomicAdd(&cnt[d.x], 1);
            atomicAdd(&cnt[d.y], 1);
            atomicAdd(&cnt[d.z], 1);
            atomicAdd(&cnt[d.w], 1);
        }
    } else {
        int b = bx - 512;
        int r = b & 255, half = (b >> 8) & 1, layer = b >> 9;
        int c = threadIdx.x;
        const float* W = layer ? (half ? Wr2 : Wl2) : (half ? Wr1 : Wl1);
        Wt[(size_t)(layer * 512 + half * 256 + c) * 256 + r] = f2b(W[r * 256 + c]);
    }
}

// n must be 32768: 1024 threads x 32 elements each (int4 loads)
__global__ __launch_bounds__(1024) void k_scan(const int* __restrict__ cnt,
                                               int* __restrict__ row_ptr,
                                               int* __restrict__ fill, int n) {
    __shared__ int sdata[1024];
    int t = threadIdx.x;
    int base = t * 32;
    int local[32];
    const int4* c4 = (const int4*)(cnt + base);
    int vals[32];
    #pragma unroll
    for (int q = 0; q < 8; q++) {
        int4 v = c4[q];
        vals[q * 4 + 0] = v.x; vals[q * 4 + 1] = v.y;
        vals[q * 4 + 2] = v.z; vals[q * 4 + 3] = v.w;
    }
    int sum = 0;
    #pragma unroll
    for (int k = 0; k < 32; k++) { local[k] = sum; sum += vals[k]; }
    sdata[t] = sum;
    __syncthreads();
    for (int off = 1; off < 1024; off <<= 1) {
        int v = (t >= off) ? sdata[t - off] : 0;
        __syncthreads();
        sdata[t] += v;
        __syncthreads();
    }
    int excl = sdata[t] - sum;
    #pragma unroll
    for (int k = 0; k < 32; k++) {
        int v = excl + local[k];
        row_ptr[base + k] = v;
        fill[base + k] = v;
    }
    if (t == 1023) row_ptr[n] = excl + sum;
}

__global__ void k_scatter(const int* __restrict__ src, const int* __restrict__ dst,
                          int* __restrict__ fill, int* __restrict__ col, int E) {
    int g = blockIdx.x * blockDim.x + threadIdx.x;
    if (g * 4 < E) {
        int4 d = ((const int4*)dst)[g];
        int4 sv = ((const int4*)src)[g];
        int p;
        p = atomicAdd(&fill[d.x], 1); col[p] = sv.x;
        p = atomicAdd(&fill[d.y], 1); col[p] = sv.y;
        p = atomicAdd(&fill[d.z], 1); col[p] = sv.z;
        p = atomicAdd(&fill[d.w], 1); col[p] = sv.w;
    }
}

// ---------------- fused MFMA GEMM: C[M,512] = A[M,K] @ Bt[512,K]^T + bias ----------------
// grid (4, M/128). 128x128 tile, BK=64. B (and bf16-A) via global_load_lds (m97).
// Epilogue: acc -> padded LDS tile -> coalesced dwordx4 stores.
template <bool AF32>
__global__ __launch_bounds__(256) void k_gemm(const void* __restrict__ Av,
                                              const bf16* __restrict__ Bt,
                                              const float* __restrict__ biasL,
                                              const float* __restrict__ biasR,
                                              bf16* __restrict__ C,
                                              int M, int K) {
    __shared__ bf16 smem[16896];      // staging: As=smem[0:8192), Bs=smem[8192:16384)
    bf16* As = smem;                  // epilogue: 128x132 padded output tile
    bf16* Bs = smem + 8192;
    const int tid  = threadIdx.x;
    const int wave = tid >> 6;
    const int lane = tid & 63;
    const int quad = lane >> 4;
    const int l16  = lane & 15;
    const int m0 = blockIdx.y * 128;
    const int n0 = blockIdx.x * 128;
    const int wm = (wave & 1) * 64;
    const int wn = (wave >> 1) * 64;

    floatx4 acc[4][4] = {};

    for (int k0 = 0; k0 < K; k0 += 64) {
        #pragma unroll
        for (int i = 0; i < 4; i++) {
            if (AF32) {
                const float* A = (const float*)Av;
                int flat = (i * 256 + tid) * 8;
                int row  = flat >> 6;
                int colk = flat & 63;
                const float* ap = A + (size_t)(m0 + row) * K + k0 + colk;
                bf16 tmp[8];
                #pragma unroll
                for (int q = 0; q < 8; q++) tmp[q] = f2b(ap[q]);
                *(short8*)&As[row * 64 + colk] = *(const short8*)tmp;
            } else {
                const bf16* A = (const bf16*)Av;
                int chunk = i * 4 + wave;
                int foff  = (chunk * 64 + lane) * 16;
                int row   = foff >> 7;
                int cole  = (foff & 127) >> 1;
                GLD_LDS16(A + (size_t)(m0 + row) * K + k0 + cole,
                          (char*)As + chunk * 1024 + lane * 16);
            }
            {
                int chunk = i * 4 + wave;
                int foff  = (chunk * 64 + lane) * 16;
                int row   = foff >> 7;
                int cole  = (foff & 127) >> 1;
                GLD_LDS16(Bt + (size_t)(n0 + row) * K + k0 + cole,
                          (char*)Bs + chunk * 1024 + lane * 16);
            }
        }
        __syncthreads();
        #pragma unroll
        for (int ks = 0; ks < 2; ks++) {
            short8 af[4], bfr[4];
            #pragma unroll
            for (int i = 0; i < 4; i++) {
                af[i]  = *(const short8*)&As[(wm + i * 16 + l16) * 64 + ks * 32 + quad * 8];
                bfr[i] = *(const short8*)&Bs[(wn + i * 16 + l16) * 64 + ks * 32 + quad * 8];
            }
            #pragma unroll
            for (int i = 0; i < 4; i++)
                #pragma unroll
                for (int j = 0; j < 4; j++)
                    acc[i][j] = __builtin_amdgcn_mfma_f32_16x16x32_bf16(af[i], bfr[j], acc[i][j], 0, 0, 0);
        }
        __syncthreads();
    }

    // C/D layout: col = lane&15, row = quad*4 + reg  [verified m89/m91]
    #pragma unroll
    for (int j = 0; j < 4; j++) {
        int lcol = wn + j * 16 + l16;
        int gcol = n0 + lcol;
        float bv = (gcol < 256) ? biasL[gcol] : biasR[gcol - 256];
        #pragma unroll
        for (int i = 0; i < 4; i++) {
            #pragma unroll
            for (int r = 0; r < 4; r++) {
                int lrow = wm + i * 16 + quad * 4 + r;
                smem[lrow * 132 + lcol] = f2b(acc[i][j][r] + bv);
            }
        }
    }
    __syncthreads();
    {
        int rl = tid >> 4;
        int cs = (tid & 15) * 8;
        #pragma unroll
        for (int p = 0; p < 8; p++) {
            int row = p * 16 + rl;
            short8 v = *(const short8*)&smem[row * 132 + cs];
            *(short8*)(C + (size_t)(m0 + row) * 512 + n0 + cs) = v;
        }
    }
}

// ---------------- GATv2 aggregation: half-wave per edge, 8 ch/lane (R9 structure) ----------------
// One wave per dst node. Lanes 0-31 = item a, 32-63 = item b of each pair.
// Within a half: 8 lanes per head (hl>>3), 8 channels per lane ((hl&7)*8).
// Item 0 = self-loop, items 1..deg = CSR edges. Max-free softmax (logits bounded),
// leaky folded into att (0.6u + 0.4|u|). 32-bit element offsets (SGPR-base addressing).
__global__ __launch_bounds__(256) void k_agg(const bf16* __restrict__ xlr,
                                             const float* __restrict__ att,
                                             const int* __restrict__ row_ptr,
                                             const int* __restrict__ col,
                                             const float* __restrict__ bias,
                                             bf16* __restrict__ out, int do_gelu) {
    int wave = threadIdx.x >> 6, lane = threadIdx.x & 63;
    int i = blockIdx.x * 4 + wave;
    int hl = lane & 31;
    int half = lane >> 5;
    unsigned f = (hl >> 3) * 64 + (hl & 7) * 8;

    float att6[8], att4[8], xr_v[8];
    {
        floatx4 a0 = *(const floatx4*)(att + f);
        floatx4 a1 = *(const floatx4*)(att + f + 4);
        #pragma unroll
        for (int j = 0; j < 4; j++) {
            att6[j]     = 0.6f * a0[j]; att4[j]     = 0.4f * a0[j];
            att6[4 + j] = 0.6f * a1[j]; att4[4 + j] = 0.4f * a1[j];
        }
        bf16 t[8];
        *(short8*)t = *(const short8*)(xlr + ((unsigned)i * 512u + 256u + f));
        #pragma unroll
        for (int j = 0; j < 8; j++) xr_v[j] = b2f(t[j]);
    }

    int e0 = row_ptr[i], e1 = row_ptr[i + 1];
    int total = 1 + (e1 - e0);   // self + in-edges

    // prologue: resolve + issue gather for pair 0; resolve col for pair 1
    int src_c = i;
    if (half == 1 && total > 1) src_c = col[e0];
    bf16 g_cur[8];
    *(short8*)g_cur = *(const short8*)(xlr + ((unsigned)src_c * 512u + f));
    int t1 = 2 + half;
    int src_n = (t1 < total) ? col[e0 + t1 - 1] : i;

    float s = 0.f, acc[8] = {};

    for (int base = 0; base < total; base += 2) {
        // issue gather for pair+1 (address resolved last iteration)
        bf16 g_nxt[8];
        *(short8*)g_nxt = *(const short8*)(xlr + ((unsigned)src_n * 512u + f));
        // resolve col for pair+2
        int t2 = base + 4 + half;
        int src_n2 = (t2 < total) ? col[e0 + t2 - 1] : i;
        // compute current pair
        bool valid = (base + half) < total;
        float xv[8], l = 0.f;
        #pragma unroll
        for (int j = 0; j < 8; j++) {
            xv[j] = b2f(g_cur[j]);
            float u = xv[j] + xr_v[j];
            l = fmaf(u, att6[j], fmaf(fabsf(u), att4[j], l));
        }
        l += __shfl_xor(l, 1, 8);
        l += __shfl_xor(l, 2, 8);
        l += __shfl_xor(l, 4, 8);
        float p = valid ? __expf(l) : 0.f;
        s += p;
        #pragma unroll
        for (int j = 0; j < 8; j++) acc[j] = fmaf(p, xv[j], acc[j]);
        // rotate pipeline
        #pragma unroll
        for (int j = 0; j < 8; j++) g_cur[j] = g_nxt[j];
        src_n = src_n2;
    }

    // combine the two halves
    s += __shfl_xor(s, 32, 64);
    #pragma unroll
    for (int j = 0; j < 8; j++) acc[j] += __shfl_xor(acc[j], 32, 64);

    if (half == 0) {
        float inv = 1.0f / (s + 1e-16f);
        bf16 ov[8];
        #pragma unroll
        for (int j = 0; j < 8; j++) {
            float v = acc[j] * inv + bias[f + j];
            if (do_gelu) v = gelu_f(v);
            ov[j] = f2b(v);
        }
        *(short8*)(out + ((unsigned)i * 256u + f)) = *(const short8*)ov;
    }
}

// ---------------- shared head-layer body (block = one (graph, 64-col chunk)) ----------------
__device__ __forceinline__ void head_body(const bf16* __restrict__ inB,
                                          const float* __restrict__ inF,
                                          const float* __restrict__ W,
                                          const float* __restrict__ bias,
                                          float* __restrict__ out,
                                          int K, int N, long long row_stride, int act,
                                          int g, int chunk, float* zin, float* red) {
    int t = threadIdx.x;
    int nc = t & 63;
    int kq = t >> 6;
    int n = chunk * 64 + nc;
    for (int k = t; k < K; k += 256)
        zin[k] = inB ? b2f(inB[(size_t)g * row_stride + k])
                     : inF[(size_t)g * row_stride + k];
    __syncthreads();
    const int klen = K >> 2;
    const int kb = kq * klen;
    float acc = 0.f;
    #pragma unroll 8
    for (int k = 0; k < klen; k++)
        acc = fmaf(zin[kb + k], W[(size_t)(kb + k) * N + n], acc);
    red[t] = acc;
    __syncthreads();
    if (kq == 0) {
        float v = red[nc] + red[nc + 64] + red[nc + 128] + red[nc + 192] + bias[n];
        if (act) v = gelu_f(v);
        out[(size_t)g * N + n] = v;
    }
}

// ---------------- fused: pool stage 1 (blocks 0..511) + head lin1 (512..1535) ----------------
__global__ __launch_bounds__(256) void k_pe1(const bf16* __restrict__ hb,
                                             float* __restrict__ part,
                                             const float* __restrict__ lin1w,
                                             const float* __restrict__ lin1b,
                                             float* __restrict__ t1, int PG) {
    __shared__ float zin[256];
    __shared__ float red[256];
    int bx = blockIdx.x;
    if (bx < 512) {
        int g = bx >> 3, p = bx & 7, c = threadIdx.x;
        int rows_per = PG / 8;
        const bf16* base = hb + ((size_t)g * PG + (size_t)p * rows_per) * 256;
        float acc = 0.f;
        for (int r = 0; r < rows_per; r++) acc += b2f(base[(size_t)r * 256 + c]);
        part[((size_t)g * 8 + p) * 256 + c] = acc;
    } else {
        int b = bx - 512;
        head_body(hb, nullptr, lin1w, lin1b, t1, 256, 1024,
                  (long long)PG * 256, 1, b >> 4, b & 15, zin, red);
    }
}

// ---------------- fused: pool stage 2 (blocks 0..63) + head lin2 (64..319) ----------------
__global__ __launch_bounds__(256) void k_pe2(const float* __restrict__ part,
                                             float* __restrict__ outPool, int PG,
                                             const float* __restrict__ t1,
                                             const float* __restrict__ lin2w,
                                             const float* __restrict__ lin2b,
                                             float* __restrict__ t2) {
    __shared__ float zin[1024];
    __shared__ float red[256];
    int bx = blockIdx.x;
    if (bx < 64) {
        int g = bx, c = threadIdx.x;
        float acc = 0.f;
        for (int p = 0; p < 8; p++) acc += part[((size_t)g * 8 + p) * 256 + c];
        outPool[g * 256 + c] = acc / (float)PG;
    } else {
        int b = bx - 64;
        head_body(nullptr, t1, lin2w, lin2b, t2, 1024, 256,
                  1024, 0, b >> 2, b & 3, zin, red);
    }
}

// ---------------- final head layer ----------------
__global__ __launch_bounds__(256) void k_fin(const float* __restrict__ t2,
                                             const float* __restrict__ finw,
                                             const float* __restrict__ finb,
                                             float* __restrict__ out) {
    __shared__ float zin[256];
    __shared__ float red[256];
    head_body(nullptr, t2, finw, finb, out, 256, 512,
              256, 0, blockIdx.x, blockIdx.y, zin, red);
}

extern "C" void kernel_launch(void* const* d_in, const int* in_sizes, int n_in,
                              void* d_out, int out_size, void* d_ws, size_t ws_size,
                              hipStream_t stream) {
    const float* x     = (const float*)d_in[0];
    const int*   ei    = (const int*)d_in[1];
    const float* w1_l  = (const float*)d_in[4];
    const float* b1_l  = (const float*)d_in[5];
    const float* w1_r  = (const float*)d_in[6];
    const float* b1_r  = (const float*)d_in[7];
    const float* att1  = (const float*)d_in[8];
    const float* bias1 = (const float*)d_in[9];
    const float* w2_l  = (const float*)d_in[10];
    const float* b2_l  = (const float*)d_in[11];
    const float* w2_r  = (const float*)d_in[12];
    const float* b2_r  = (const float*)d_in[13];
    const float* att2  = (const float*)d_in[14];
    const float* bias2 = (const float*)d_in[15];
    const float* lin1w = (const float*)d_in[16];
    const float* lin1b = (const float*)d_in[17];
    const float* lin2w = (const float*)d_in[18];
    const float* lin2b = (const float*)d_in[19];
    const float* finw  = (const float*)d_in[20];
    const float* finb  = (const float*)d_in[21];

    const int N  = in_sizes[0] / 256;   // 32768
    const int E  = in_sizes[1] / 2;     // 524288
    const int NG = 64;
    const int PG = N / NG;              // 512

    // workspace layout (~52.5 MiB), 16B-aligned blocks
    char* ws = (char*)d_ws;
    size_t off = 0;
    bf16* xlr = (bf16*)(ws + off); off += (size_t)N * 512 * 2;    // 32 MiB [xl|xr]
    bf16* hb  = (bf16*)(ws + off); off += (size_t)N * 256 * 2;    // 16 MiB (h1 then h2)
    bf16* wt  = (bf16*)(ws + off); off += 2 * 512 * 256 * 2;      // 512 KiB both layers' Wt
    int* row_ptr = (int*)(ws + off); off += (size_t)(N + 4) * 4;
    int* cnt     = (int*)(ws + off); off += (size_t)N * 4;
    int* fill    = (int*)(ws + off); off += (size_t)N * 4;
    int* col     = (int*)(ws + off); off += (size_t)E * 4;
    float* pws   = (float*)(ws + off); off += (size_t)NG * 8 * 256 * 4;  // pool partials
    float* t1    = (float*)(ws + off); off += (size_t)NG * 1024 * 4;
    float* t2    = (float*)(ws + off); off += (size_t)NG * 256 * 4;

    const int* srcv = ei;
    const int* dstv = ei + E;

    // --- CSR count + weight transposes (one launch) ---
    hipMemsetAsync(cnt, 0, (size_t)N * 4, stream);
    k_count_tr<<<512 + 1024, 256, 0, stream>>>(dstv, cnt, E,
                                               w1_l, w1_r, w2_l, w2_r, wt);
    k_scan   <<<1, 1024, 0, stream>>>(cnt, row_ptr, fill, N);
    k_scatter<<<E / 1024, 256, 0, stream>>>(srcv, dstv, fill, col, E);

    dim3 gg(4, N / 128);   // fused L/R: N-dim 512
    // --- layer 1 (A = x fp32) ---
    k_gemm<true><<<gg, 256, 0, stream>>>(x, wt, b1_l, b1_r, xlr, N, 256);
    k_agg<<<N / 4, 256, 0, stream>>>(xlr, att1, row_ptr, col, bias1, hb, 1);  // + GELU

    // --- layer 2 (A = h1 bf16) ---
    k_gemm<false><<<gg, 256, 0, stream>>>(hb, wt + 512 * 256, b2_l, b2_r, xlr, N, 256);
    k_agg<<<N / 4, 256, 0, stream>>>(xlr, att2, row_ptr, col, bias2, hb, 0);  // h2

    float* outp = (float*)d_out;
    // --- pool1 + head lin1 (one launch) ---
    k_pe1<<<512 + 1024, 256, 0, stream>>>(hb, pws, lin1w, lin1b, t1, PG);
    // --- pool2 (-> d_out[64*512..]) + head lin2 (one launch) ---
    k_pe2<<<64 + 256, 256, 0, stream>>>(pws, outp + 64 * 512, PG, t1, lin2w, lin2b, t2);
    // --- final head layer -> d_out[0..64*512) ---
    dim3 gf(NG, 512 / 64);
    k_fin<<<gf, 256, 0, stream>>>(t2, finw, finb, outp);
}